// Round 6
// baseline (173.884 us; speedup 1.0000x reference)
//
#include <hip/hip_runtime.h>

#define Tn 512
#define Nn 1024
#define Hn 1024
#define Vn 96103
#define NHEADS 16
#define SPLITS 16
#define CHUNK 6007   // ceil(96103/16)
#define TV (49204736u)   // Tn*Vn

#define HS_BLKS 512          // headsum: T*N/4 / 256
#define EW_BLKS 1024         // one per encoder token
#define SP_BLKS (SPLITS*Tn)  // stat/exp pass: 8192
#define K0_BLKS (HS_BLKS + EW_BLKS + SP_BLKS)

typedef float f4 __attribute__((ext_vector_type(4)));
typedef unsigned short us4 __attribute__((ext_vector_type(4)));
typedef unsigned short us8 __attribute__((ext_vector_type(8)));

__device__ __forceinline__ unsigned short f2bf(float x) {   // RNE f32->bf16
  unsigned u = __float_as_uint(x);
  return (unsigned short)((u + 0x7FFFu + ((u >> 16) & 1u)) >> 16);
}
__device__ __forceinline__ float bf2f(unsigned short h) {
  return __uint_as_float(((unsigned)h) << 16);
}

// ================== PATH B (large ws): exp-buffer pipeline ==================

// ---- K0b: headsum+colinit | ew | exp+sum pass ----
__global__ __launch_bounds__(256) void k0b(const float* __restrict__ attn,
                                           const float* __restrict__ enc,
                                           const float* __restrict__ w,
                                           const float* __restrict__ lg,
                                           float* __restrict__ ca,
                                           float* __restrict__ ew,
                                           float* __restrict__ part_s,
                                           int* __restrict__ col2n,
                                           unsigned short* __restrict__ ebuf) {
  const int b = blockIdx.x, tid = threadIdx.x;

  if (b < HS_BLKS) {
    int i = b * 256 + tid;
    if (i < Vn) col2n[i] = -1;
    const f4* a4 = (const f4*)attn;
    const int slice = (Tn * Nn) / 4;
    f4 acc = __builtin_nontemporal_load(&a4[i]);
#pragma unroll
    for (int h = 1; h < NHEADS; ++h)
      acc += __builtin_nontemporal_load(&a4[h * slice + i]);
    ((f4*)ca)[i] = acc * (1.0f / 16.0f);
    return;
  }

  if (b < HS_BLKS + EW_BLKS) {
    int n = b - HS_BLKS;
    float4 r = ((const float4*)(enc + n * Hn))[tid];
    float4 ww = ((const float4*)w)[tid];
    float p = r.x * ww.x + r.y * ww.y + r.z * ww.z + r.w * ww.w;
    for (int off = 32; off > 0; off >>= 1) p += __shfl_down(p, off, 64);
    __shared__ float lds[4];
    int lane = tid & 63, wv = tid >> 6;
    if (lane == 0) lds[wv] = p;
    __syncthreads();
    if (tid == 0) ew[n] = lds[0] + lds[1] + lds[2] + lds[3];
    return;
  }

  // ---- exp pass: chunk c of row t -> ebuf bf16 + partial sum ----
  {
    int rem = b - HS_BLKS - EW_BLKS;
    const int c = rem & (SPLITS - 1), t = rem >> 4;
    const unsigned vbeg = c * CHUNK;
    const unsigned vend = min(vbeg + CHUNK, (unsigned)Vn);
    const unsigned beg = (unsigned)t * Vn + vbeg;
    const unsigned end = (unsigned)t * Vn + vend;
    const unsigned beg4 = (beg + 3u) & ~3u;
    const unsigned end4 = end & ~3u;

    float s = 0.0f;
    for (unsigned i = beg + tid; i < beg4; i += 256) {
      float e = __expf(__builtin_nontemporal_load(&lg[i]));
      s += e; ebuf[i] = f2bf(e);
    }
    const f4* lg4 = (const f4*)lg;
    us4* eb4 = (us4*)ebuf;
    for (unsigned i4 = beg4 / 4 + tid; i4 < end4 / 4; i4 += 256) {
      f4 a = __builtin_nontemporal_load(&lg4[i4]);
      float e0 = __expf(a[0]), e1 = __expf(a[1]), e2 = __expf(a[2]), e3 = __expf(a[3]);
      s += (e0 + e1) + (e2 + e3);
      us4 o; o[0] = f2bf(e0); o[1] = f2bf(e1); o[2] = f2bf(e2); o[3] = f2bf(e3);
      eb4[i4] = o;
    }
    for (unsigned i = end4 + tid; i < end; i += 256) {
      float e = __expf(__builtin_nontemporal_load(&lg[i]));
      s += e; ebuf[i] = f2bf(e);
    }
    for (int off = 32; off > 0; off >>= 1) s += __shfl_down(s, off, 64);
    __shared__ float ls[4];
    int lane = tid & 63, wv = tid >> 6;
    if (lane == 0) ls[wv] = s;
    __syncthreads();
    if (tid == 0) part_s[t * SPLITS + c] = ls[0] + ls[1] + ls[2] + ls[3];
  }
}

// ---- K1b: per-row gen + sum-combine -> params(g, inv, 1-g); block Tn scatters ----
__global__ __launch_bounds__(256) void k1b(const float* __restrict__ ca,
                                           const float* __restrict__ ew,
                                           const float* __restrict__ dh,
                                           const float* __restrict__ de,
                                           const float* __restrict__ w,
                                           const float* __restrict__ b,
                                           const float* __restrict__ part_s,
                                           const int* __restrict__ ids,
                                           int* __restrict__ col2n,
                                           float4* __restrict__ params,
                                           float* __restrict__ out_gen) {
  const int t = blockIdx.x, tid = threadIdx.x;
  if (t == Tn) {
    for (int n = tid; n < Nn; n += 256)
      atomicMax(&col2n[ids[n]], n);            // numpy last-write-wins == max n
    return;
  }
  float4 c4 = ((const float4*)(ca + t * Nn))[tid];
  float4 e4 = ((const float4*)ew)[tid];
  float p = c4.x * e4.x + c4.y * e4.y + c4.z * e4.z + c4.w * e4.w;
  float4 h4 = ((const float4*)(dh + t * Hn))[tid];
  float4 w1 = ((const float4*)(w + Hn))[tid];
  p += h4.x * w1.x + h4.y * w1.y + h4.z * w1.z + h4.w * w1.w;
  float4 d4 = ((const float4*)(de + t * Hn))[tid];
  float4 w2 = ((const float4*)(w + 2 * Hn))[tid];
  p += d4.x * w2.x + d4.y * w2.y + d4.z * w2.z + d4.w * w2.w;
  for (int off = 32; off > 0; off >>= 1) p += __shfl_down(p, off, 64);
  __shared__ float lds[4];
  int lane = tid & 63, wv = tid >> 6;
  if (lane == 0) lds[wv] = p;
  __syncthreads();
  if (tid == 0) {
    float z = lds[0] + lds[1] + lds[2] + lds[3] + b[0];
    float g = 1.0f / (1.0f + __expf(-z));
    float S = 0.0f;
#pragma unroll
    for (int c = 0; c < SPLITS; ++c) S += part_s[t * SPLITS + c];
    out_gen[t] = g;
    params[t] = make_float4(g, 1.0f / S, 1.0f - g, 0.0f);
  }
}

// ---- K2b: reverse-order, 8 elems/thread: out = g*e*inv + (1-g)*copy ----
__global__ __launch_bounds__(256) void k2b(const unsigned short* __restrict__ ebuf,
                                           const float* __restrict__ ca,
                                           const float4* __restrict__ params,
                                           const int* __restrict__ col2n,
                                           float* __restrict__ out) {
  const unsigned total8 = TV / 8u;            // 6150592
  const us8* eb8 = (const us8*)ebuf;
  f4* out4 = (f4*)out;
  const unsigned stride = gridDim.x * 256u;
  for (unsigned j = blockIdx.x * 256u + threadIdx.x; j < total8; j += stride) {
    unsigned i8 = total8 - 1u - j;            // reverse: consume L3-hot tail first
    unsigned i0 = i8 * 8u;
    unsigned t = i0 / (unsigned)Vn;
    unsigned v = i0 - t * (unsigned)Vn;
    us8 e8 = eb8[i8];                          // regular (cached) load
    f4 r0, r1;
    if (v + 7u < (unsigned)Vn) {               // group within one row
      float4 P = params[t];                    // (g, inv, 1-g, _)
      const float* cat = ca + t * Nn;
#pragma unroll
      for (int k = 0; k < 8; ++k) {
        float val = P.x * bf2f(e8[k]) * P.y;
        int n = col2n[v + k];
        if (n >= 0) val += P.z * cat[n];
        if (k < 4) r0[k] = val; else r1[k - 4] = val;
      }
    } else {                                   // row-spanning (once per row)
#pragma unroll
      for (int k = 0; k < 8; ++k) {
        unsigned idx = i0 + k;
        unsigned tt = idx / (unsigned)Vn;
        unsigned vv = idx - tt * (unsigned)Vn;
        float4 P = params[tt];
        float val = P.x * bf2f(e8[k]) * P.y;
        int n = col2n[vv];
        if (n >= 0) val += P.z * ca[tt * Nn + n];
        if (k < 4) r0[k] = val; else r1[k - 4] = val;
      }
    }
    __builtin_nontemporal_store(r0, &out4[i8 * 2u]);
    __builtin_nontemporal_store(r1, &out4[i8 * 2u + 1u]);
  }
}

// ================== PATH A (fallback, small ws): R5 pipeline ==================

__global__ __launch_bounds__(256) void k0a(const float* __restrict__ attn,
                                           const float* __restrict__ enc,
                                           const float* __restrict__ w,
                                           const float* __restrict__ lg,
                                           float* __restrict__ ca,
                                           float* __restrict__ ew,
                                           float* __restrict__ part_m,
                                           float* __restrict__ part_s,
                                           int* __restrict__ col2n) {
  const int b = blockIdx.x, tid = threadIdx.x;
  if (b < HS_BLKS) {
    int i = b * 256 + tid;
    if (i < Vn) col2n[i] = -1;
    const f4* a4 = (const f4*)attn;
    const int slice = (Tn * Nn) / 4;
    f4 acc = __builtin_nontemporal_load(&a4[i]);
#pragma unroll
    for (int h = 1; h < NHEADS; ++h)
      acc += __builtin_nontemporal_load(&a4[h * slice + i]);
    ((f4*)ca)[i] = acc * (1.0f / 16.0f);
    return;
  }
  if (b < HS_BLKS + EW_BLKS) {
    int n = b - HS_BLKS;
    float4 r = ((const float4*)(enc + n * Hn))[tid];
    float4 ww = ((const float4*)w)[tid];
    float p = r.x * ww.x + r.y * ww.y + r.z * ww.z + r.w * ww.w;
    for (int off = 32; off > 0; off >>= 1) p += __shfl_down(p, off, 64);
    __shared__ float lds[4];
    int lane = tid & 63, wv = tid >> 6;
    if (lane == 0) lds[wv] = p;
    __syncthreads();
    if (tid == 0) ew[n] = lds[0] + lds[1] + lds[2] + lds[3];
    return;
  }
  {
    int rem = b - HS_BLKS - EW_BLKS;
    const int c = rem & (SPLITS - 1), t = rem >> 4;
    const unsigned vbeg = c * CHUNK;
    const unsigned vend = min(vbeg + CHUNK, (unsigned)Vn);
    const unsigned beg = (unsigned)t * Vn + vbeg;
    const unsigned end = (unsigned)t * Vn + vend;
    const unsigned beg4 = (beg + 3u) & ~3u;
    const unsigned end4 = end & ~3u;
    float m = -INFINITY, s = 0.0f;
    for (unsigned i = beg + tid; i < beg4; i += 256) {
      float x = lg[i];
      if (x > m) { s *= __expf(m - x); m = x; }
      s += __expf(x - m);
    }
    const float4* lg4 = (const float4*)lg;
    for (unsigned i4 = beg4 / 4 + tid; i4 < end4 / 4; i4 += 256) {
      float4 a = lg4[i4];
      float mx = fmaxf(fmaxf(a.x, a.y), fmaxf(a.z, a.w));
      if (mx > m) { s *= __expf(m - mx); m = mx; }
      s += __expf(a.x - m) + __expf(a.y - m) + __expf(a.z - m) + __expf(a.w - m);
    }
    for (unsigned i = end4 + tid; i < end; i += 256) {
      float x = lg[i];
      if (x > m) { s *= __expf(m - x); m = x; }
      s += __expf(x - m);
    }
    for (int off = 32; off > 0; off >>= 1) {
      float mo = __shfl_down(m, off, 64);
      float so = __shfl_down(s, off, 64);
      float M = fmaxf(m, mo);
      s = s * __expf(m - M) + so * __expf(mo - M);
      m = M;
    }
    __shared__ float lm[4], ls[4];
    int lane = tid & 63, wv = tid >> 6;
    if (lane == 0) { lm[wv] = m; ls[wv] = s; }
    __syncthreads();
    if (tid == 0) {
      float M = fmaxf(fmaxf(lm[0], lm[1]), fmaxf(lm[2], lm[3]));
      float S = ls[0] * __expf(lm[0] - M) + ls[1] * __expf(lm[1] - M) +
                ls[2] * __expf(lm[2] - M) + ls[3] * __expf(lm[3] - M);
      part_m[t * SPLITS + c] = M;
      part_s[t * SPLITS + c] = S;
    }
  }
}

__global__ __launch_bounds__(256) void k1a(const float* __restrict__ ca,
                                           const float* __restrict__ ew,
                                           const float* __restrict__ dh,
                                           const float* __restrict__ de,
                                           const float* __restrict__ w,
                                           const float* __restrict__ b,
                                           const float* __restrict__ part_m,
                                           const float* __restrict__ part_s,
                                           const int* __restrict__ ids,
                                           int* __restrict__ col2n,
                                           float4* __restrict__ params,
                                           float* __restrict__ out_gen) {
  const int t = blockIdx.x, tid = threadIdx.x;
  if (t == Tn) {
    for (int n = tid; n < Nn; n += 256) atomicMax(&col2n[ids[n]], n);
    return;
  }
  float4 c4 = ((const float4*)(ca + t * Nn))[tid];
  float4 e4 = ((const float4*)ew)[tid];
  float p = c4.x * e4.x + c4.y * e4.y + c4.z * e4.z + c4.w * e4.w;
  float4 h4 = ((const float4*)(dh + t * Hn))[tid];
  float4 w1 = ((const float4*)(w + Hn))[tid];
  p += h4.x * w1.x + h4.y * w1.y + h4.z * w1.z + h4.w * w1.w;
  float4 d4 = ((const float4*)(de + t * Hn))[tid];
  float4 w2 = ((const float4*)(w + 2 * Hn))[tid];
  p += d4.x * w2.x + d4.y * w2.y + d4.z * w2.z + d4.w * w2.w;
  for (int off = 32; off > 0; off >>= 1) p += __shfl_down(p, off, 64);
  __shared__ float lds[4];
  int lane = tid & 63, wv = tid >> 6;
  if (lane == 0) lds[wv] = p;
  __syncthreads();
  if (tid == 0) {
    float z = lds[0] + lds[1] + lds[2] + lds[3] + b[0];
    float g = 1.0f / (1.0f + __expf(-z));
    float M = -INFINITY, S = 0.0f;
#pragma unroll
    for (int c = 0; c < SPLITS; ++c) {
      float mp = part_m[t * SPLITS + c];
      float sp = part_s[t * SPLITS + c];
      float Mn = fmaxf(M, mp);
      S = S * __expf(M - Mn) + sp * __expf(mp - Mn);
      M = Mn;
    }
    out_gen[t] = g;
    params[t] = make_float4(g, M, 1.0f / S, 1.0f - g);
  }
}

__global__ __launch_bounds__(256) void k2a(const float* __restrict__ lg,
                                           const float* __restrict__ ca,
                                           const float4* __restrict__ params,
                                           const int* __restrict__ col2n,
                                           float* __restrict__ out) {
  const unsigned total4 = TV / 4u;
  const f4* lg4 = (const f4*)lg;
  f4* out4 = (f4*)out;
  for (unsigned i4 = blockIdx.x * 256u + threadIdx.x; i4 < total4;
       i4 += gridDim.x * 256u) {
    unsigned i0 = i4 * 4u;
    unsigned t = i0 / (unsigned)Vn;
    unsigned v = i0 - t * (unsigned)Vn;
    f4 x = __builtin_nontemporal_load(&lg4[i4]);
    f4 r;
    if (v + 3u < (unsigned)Vn) {
      float4 P = params[t];
      int n0 = col2n[v], n1 = col2n[v + 1], n2 = col2n[v + 2], n3 = col2n[v + 3];
      r[0] = P.x * __expf(x[0] - P.y) * P.z;
      r[1] = P.x * __expf(x[1] - P.y) * P.z;
      r[2] = P.x * __expf(x[2] - P.y) * P.z;
      r[3] = P.x * __expf(x[3] - P.y) * P.z;
      const float* cat = ca + t * Nn;
      if (n0 >= 0) r[0] += P.w * cat[n0];
      if (n1 >= 0) r[1] += P.w * cat[n1];
      if (n2 >= 0) r[2] += P.w * cat[n2];
      if (n3 >= 0) r[3] += P.w * cat[n3];
    } else {
#pragma unroll
      for (int j = 0; j < 4; ++j) {
        unsigned idx = i0 + j;
        unsigned tt = idx / (unsigned)Vn;
        unsigned vv = idx - tt * (unsigned)Vn;
        float4 P = params[tt];
        int n = col2n[vv];
        float val = P.x * __expf(x[j] - P.y) * P.z;
        if (n >= 0) val += P.w * ca[tt * Nn + n];
        r[j] = val;
      }
    }
    __builtin_nontemporal_store(r, &out4[i4]);
  }
}

extern "C" void kernel_launch(void* const* d_in, const int* in_sizes, int n_in,
                              void* d_out, int out_size, void* d_ws, size_t ws_size,
                              hipStream_t stream) {
  const float* attn = (const float*)d_in[0];
  const float* enc  = (const float*)d_in[1];
  const float* dh   = (const float*)d_in[2];
  const float* de   = (const float*)d_in[3];
  const float* lg   = (const float*)d_in[4];
  const int*   ids  = (const int*)d_in[5];
  const float* w    = (const float*)d_in[6];
  const float* b    = (const float*)d_in[7];
  float* out = (float*)d_out;

  const size_t need = (size_t)TV * 2 + (8u << 20);   // ebuf + ~8MB small buffers

  if (ws_size >= need) {
    // PATH B layout: ebuf first (16B aligned)
    unsigned short* ebuf = (unsigned short*)d_ws;     // TV bf16
    float4* params = (float4*)(ebuf + TV);            // T
    float* ca     = (float*)(params + Tn);            // T*N
    float* ew     = ca + Tn * Nn;                     // N
    float* part_s = ew + Nn;                          // T*SPLITS
    int*   col2n  = (int*)(part_s + Tn * SPLITS);     // V

    hipLaunchKernelGGL(k0b, dim3(K0_BLKS), dim3(256), 0, stream,
                       attn, enc, w, lg, ca, ew, part_s, col2n, ebuf);
    hipLaunchKernelGGL(k1b, dim3(Tn + 1), dim3(256), 0, stream,
                       ca, ew, dh, de, w, b, part_s, ids, col2n, params, out);
    hipLaunchKernelGGL(k2b, dim3(4096), dim3(256), 0, stream,
                       ebuf, ca, params, col2n, out + Tn);
  } else {
    // PATH A layout (R5)
    float4* params = (float4*)d_ws;
    float* ca     = (float*)(params + Tn);
    float* ew     = ca + Tn * Nn;
    float* part_m = ew + Nn;
    float* part_s = part_m + Tn * SPLITS;
    int*   col2n  = (int*)(part_s + Tn * SPLITS);

    hipLaunchKernelGGL(k0a, dim3(K0_BLKS), dim3(256), 0, stream,
                       attn, enc, w, lg, ca, ew, part_m, part_s, col2n);
    hipLaunchKernelGGL(k1a, dim3(Tn + 1), dim3(256), 0, stream,
                       ca, ew, dh, de, w, b, part_m, part_s, ids, col2n, params, out);
    hipLaunchKernelGGL(k2a, dim3(4096), dim3(256), 0, stream,
                       lg, ca, params, col2n, out + Tn);
  }
}